// Round 1
// baseline (792.342 us; speedup 1.0000x reference)
//
#include <hip/hip_runtime.h>

typedef unsigned short u16;
typedef unsigned int u32;
typedef __bf16 bf16x8 __attribute__((ext_vector_type(8)));
typedef float f32x4 __attribute__((ext_vector_type(4)));

// ---------------- problem constants ----------------
constexpr int NB = 64, CH3 = 3;
constexpr int PLANES = NB * CH3;          // 192
constexpr int PPIX = 224 * 224;           // 50176 per plane
constexpr int PP = 14 * 14;               // 196 pixels per image
constexpr int NPX = NB * PP;              // 12544 total pixels
constexpr int D = 540, DPAD = 640;
constexpr int K2 = 576;                   // padded K for w2 GEMM
constexpr int CIPAD = 1088;               // 1080 padded
constexpr int KCONV = 9 * CIPAD;          // 9792
constexpr int BINS = 2048;
constexpr int RANK1 = 49674;              // 1-indexed order stats for q=0.99
constexpr int RANK2 = 49675;

// ---------------- workspace layout (bytes) ----------------
constexpr size_t SZ_PLANE = (size_t)PLANES * PPIX * 4;        // 38,535,168
constexpr size_t OFF_A1   = 0;
constexpr size_t OFF_A2   = OFF_A1 + SZ_PLANE;
constexpr size_t OFF_A3   = OFF_A2 + SZ_PLANE;
constexpr size_t OFF_HIST = OFF_A3 + SZ_PLANE;
constexpr size_t SZ_HIST  = (size_t)10 * PLANES * BINS * 4;   // 15,728,640
constexpr size_t OFF_SUMS = OFF_HIST + SZ_HIST;               // 192 floats
constexpr size_t OFF_INVS = OFF_SUMS + 768;                   // 1920 floats
constexpr size_t OFF_EPIX = OFF_INVS + 7680;                  // NPX*32 f32
constexpr size_t OFF_HBF  = OFF_EPIX + (size_t)NPX * 32 * 4;  // NPX*576 bf16
constexpr size_t OFF_GIT  = OFF_HBF + (size_t)NPX * K2 * 2;   // 64*256*1088 bf16
constexpr size_t SZ_GIT   = (size_t)NB * 256 * CIPAD * 2;     // 35,651,584
constexpr size_t OFF_WGB  = OFF_GIT + SZ_GIT;                 // 640*9792 bf16
constexpr size_t OFF_W2B  = OFF_WGB + (size_t)DPAD * KCONV * 2;
constexpr size_t OFF_MARR = OFF_W2B + (size_t)DPAD * K2 * 2;  // NB*540*196 f32

__device__ __forceinline__ u16 f2bf(float x) {
  union { float f; u32 u; } c; c.f = x;
  u32 r = c.u + 0x7FFFu + ((c.u >> 16) & 1u);
  return (u16)(r >> 16);
}

__device__ __forceinline__ float wred64(float v) {
  v += __shfl_down(v, 32, 64); v += __shfl_down(v, 16, 64);
  v += __shfl_down(v, 8, 64);  v += __shfl_down(v, 4, 64);
  v += __shfl_down(v, 2, 64);  v += __shfl_down(v, 1, 64);
  return v;
}

__device__ __forceinline__ void cp16(const void* g, void* l) {
  __builtin_amdgcn_global_load_lds((const __attribute__((address_space(1))) u32*)g,
                                   (__attribute__((address_space(3))) u32*)l, 16, 0, 0);
}

// ---------------- SWT level: a_j -> a_{j+1}, detail-band histograms ----------------
__global__ __launch_bounds__(256) void swt_kernel(const float* __restrict__ src,
    float* __restrict__ dst, int* __restrict__ hist, float* __restrict__ sums,
    int d, int is_last)
{
  __shared__ int lh[3 * BINS];
  __shared__ float wsum[4];
  const int t = threadIdx.x;
  for (int i = t; i < 3 * BINS; i += 256) lh[i] = 0;
  __syncthreads();
  const int plane = blockIdx.x >> 2, chunk = blockIdx.x & 3;
  const float* Pp = src + (size_t)plane * PPIX;
  float* Q = dst + (size_t)plane * PPIX;
  float asum = 0.f;
  for (int i = 0; i < 49; ++i) {
    int idx = chunk * 12544 + i * 256 + t;
    int h = idx / 224, w = idx - h * 224;
    int w2 = w + d; if (w2 >= 224) w2 -= 224;
    int h2 = h + d; if (h2 >= 224) h2 -= 224;
    float p00 = Pp[idx];
    float p01 = Pp[h * 224 + w2];
    float p10 = Pp[h2 * 224 + w];
    float p11 = Pp[h2 * 224 + w2];
    float s0 = p00 + p01, s1 = p10 + p11, d0 = p00 - p01, d1 = p10 - p11;
    float cA = (s0 + s1) * 0.5f;
    float cH = (s0 - s1) * 0.5f;
    float cV = (d0 + d1) * 0.5f;
    float cD = (d0 - d1) * 0.5f;
    Q[idx] = cA;
    atomicAdd(&lh[__float_as_uint(fabsf(cH)) >> 20], 1);
    atomicAdd(&lh[BINS + (__float_as_uint(fabsf(cV)) >> 20)], 1);
    atomicAdd(&lh[2 * BINS + (__float_as_uint(fabsf(cD)) >> 20)], 1);
    asum += cA;
  }
  __syncthreads();
  for (int i = t; i < 3 * BINS; i += 256) {
    int v = lh[i];
    if (v) {
      int b = i >> 11, bin = i & (BINS - 1);
      atomicAdd(&hist[(b * PLANES + plane) * BINS + bin], v);
    }
  }
  if (is_last) {
    asum = wred64(asum);
    if ((t & 63) == 0) wsum[t >> 6] = asum;
    __syncthreads();
    if (t == 0) atomicAdd(&sums[plane], wsum[0] + wsum[1] + wsum[2] + wsum[3]);
  }
}

// ---------------- LL band histogram: |a3 - mu| ----------------
__global__ __launch_bounds__(256) void ll_hist_kernel(const float* __restrict__ a3,
    const float* __restrict__ sums, int* __restrict__ hist9)
{
  __shared__ int lh[BINS];
  const int t = threadIdx.x;
  for (int i = t; i < BINS; i += 256) lh[i] = 0;
  __syncthreads();
  const int plane = blockIdx.x >> 2, chunk = blockIdx.x & 3;
  const float mu = sums[plane] * (1.f / 50176.f);
  const float* Pp = a3 + (size_t)plane * PPIX;
  for (int i = 0; i < 49; ++i) {
    int idx = chunk * 12544 + i * 256 + t;
    float v = fabsf(Pp[idx] - mu);
    atomicAdd(&lh[__float_as_uint(v) >> 20], 1);
  }
  __syncthreads();
  for (int i = t; i < BINS; i += 256) {
    int v = lh[i];
    if (v) atomicAdd(&hist9[plane * BINS + i], v);
  }
}

// ---------------- quantile from histogram ----------------
__global__ __launch_bounds__(256) void quant_kernel(const int* __restrict__ hist,
    float* __restrict__ invs)
{
  const int g = blockIdx.x;
  const int* hrow = hist + (size_t)g * BINS;
  __shared__ int part[256];
  const int t = threadIdx.x;
  int sacc = 0;
  for (int j = 0; j < 8; ++j) sacc += hrow[t * 8 + j];
  part[t] = sacc;
  __syncthreads();
  if (t == 0) {
    float v[2] = {0.f, 0.f};
    int cum = 0, target = 0;
    for (int sg = 0; sg < 256 && target < 2; ++sg) {
      int pc = part[sg];
      int need = (target == 0) ? RANK1 : RANK2;
      if (cum + pc < need) { cum += pc; continue; }
      for (int b = sg * 8; b < sg * 8 + 8; ++b) {
        int c = hrow[b];
        while (target < 2) {
          int rank = (target == 0) ? RANK1 : RANK2;
          if (cum + c >= rank) {
            float lo = __uint_as_float((u32)b << 20);
            float hi = __uint_as_float((u32)(b + 1) << 20);
            float fr = ((float)(rank - cum) - 0.5f) / (float)c;
            fr = fminf(fmaxf(fr, 0.f), 1.f);
            v[target] = lo + (hi - lo) * fr;
            ++target;
          } else break;
        }
        cum += c;
        if (target == 2) break;
      }
    }
    float s = 0.75f * v[0] + 0.25f * v[1];
    invs[g] = 1.f / (s + 1e-4f);
  }
}

// ---------------- pooling: recompute bands, normalize, 16x16 mean -> e_pix ----------------
__global__ __launch_bounds__(256) void pool_kernel(const float* __restrict__ frames,
    const float* __restrict__ a1, const float* __restrict__ a2, const float* __restrict__ a3,
    const float* __restrict__ sums, const float* __restrict__ invs, float* __restrict__ epix)
{
  const int job = blockIdx.x;
  const int plane = job >> 2, sub = job & 3;
  const int n = plane / 3, c = plane - 3 * (plane / 3);
  const int t = threadIdx.x, wave = t >> 6, lane = t & 63;
  const float* Pp; int d = 1;
  if (sub == 0) Pp = frames;
  else if (sub == 1) { Pp = a1; d = 2; }
  else if (sub == 2) { Pp = a2; d = 4; }
  else Pp = a3;
  Pp += (size_t)plane * PPIX;
  float mu = 0.f, i0, i1 = 0.f, i2 = 0.f;
  if (sub < 3) {
    i0 = invs[(sub * 3 + 0) * PLANES + plane];
    i1 = invs[(sub * 3 + 1) * PLANES + plane];
    i2 = invs[(sub * 3 + 2) * PLANES + plane];
  } else {
    mu = sums[plane] * (1.f / 50176.f);
    i0 = invs[9 * PLANES + plane];
  }
  const int tx = lane & 15, ty0 = (lane >> 4) * 4;
  for (int it = 0; it < 49; ++it) {
    int widx = it * 4 + wave;
    int wy = widx / 14, wx = widx - wy * 14;
    float aH = 0.f, aV = 0.f, aD = 0.f;
    for (int r = 0; r < 4; ++r) {
      int h = wy * 16 + ty0 + r, w = wx * 16 + tx;
      if (sub < 3) {
        int w2 = w + d; if (w2 >= 224) w2 -= 224;
        int h2 = h + d; if (h2 >= 224) h2 -= 224;
        float p00 = Pp[h * 224 + w], p01 = Pp[h * 224 + w2];
        float p10 = Pp[h2 * 224 + w], p11 = Pp[h2 * 224 + w2];
        float s0 = p00 + p01, s1 = p10 + p11, d0 = p00 - p01, d1 = p10 - p11;
        aH += s0 - s1; aV += d0 + d1; aD += d0 - d1;
      } else {
        aH += Pp[h * 224 + w] - mu;
      }
    }
    aH = wred64(aH);
    if (sub < 3) { aV = wred64(aV); aD = wred64(aD); }
    if (lane == 0) {
      int px = n * 196 + widx;
      float* e = epix + (size_t)px * 32;
      if (sub < 3) {
        constexpr float sc = 0.5f / 256.f;
        e[(sub * 3 + 0) * 3 + c] = aH * sc * i0;
        e[(sub * 3 + 1) * 3 + c] = aV * sc * i1;
        e[(sub * 3 + 2) * 3 + c] = aD * sc * i2;
      } else {
        e[27 + c] = aH * (1.f / 256.f) * i0;
        e[30] = 0.f; e[31] = 0.f;
      }
    }
  }
}

// ---------------- weight packing ----------------
__global__ __launch_bounds__(256) void pack_wg_kernel(const float* __restrict__ wg,
    u16* __restrict__ wgb)
{
  int tid = blockIdx.x * 256 + threadIdx.x;   // < 640*9792
  int oc = tid / KCONV, k = tid - oc * KCONV;
  int tap = k / CIPAD, ci = k - tap * CIPAD;
  float v = (oc < 540 && ci < 1080) ? wg[(oc * 1080 + ci) * 9 + tap] : 0.f;
  wgb[tid] = f2bf(v);
}

__global__ __launch_bounds__(256) void pack_w2_kernel(const float* __restrict__ w2,
    u16* __restrict__ w2b)
{
  int tid = blockIdx.x * 256 + threadIdx.x;   // < 640*576
  int oc = tid / K2, cc = tid - oc * K2;
  float v = (oc < 540 && cc < 540) ? w2[oc * 540 + cc] : 0.f;
  w2b[tid] = f2bf(v);
}

__global__ __launch_bounds__(256) void fill_git_kernel(const float* __restrict__ tclip,
    u16* __restrict__ git)
{
  int tid = blockIdx.x * 256 + threadIdx.x;   // = (n*540+ci)*196+q
  float v = tclip[tid];
  int q = tid % 196;
  int rest = tid / 196;
  int ci = rest % 540;
  int n = rest / 540;
  int y = q / 14, x = q - y * 14;
  git[((n * 16 + 1 + y) * 16 + 1 + x) * CIPAD + ci] = f2bf(v);
}

// ---------------- GEMM1: h = relu(w1 @ e_pix + b1), fp32, out bf16 [px][576] ----------------
__global__ __launch_bounds__(256) void gemm1_kernel(const float* __restrict__ epix,
    const float* __restrict__ w1, const float* __restrict__ b1, u16* __restrict__ hbf)
{
  __shared__ float es[64][33];
  __shared__ float w1s[128][33];
  const int t = threadIdx.x;
  const int px0 = blockIdx.x * 64, oc0 = blockIdx.y * 128;
  for (int i = t; i < 64 * 32; i += 256) { int r = i >> 5, cc = i & 31; es[r][cc] = epix[(size_t)(px0 + r) * 32 + cc]; }
  for (int i = t; i < 128 * 32; i += 256) {
    int r = i >> 5, cc = i & 31; int oc = oc0 + r;
    w1s[r][cc] = (oc < 540 && cc < 30) ? w1[oc * 30 + cc] : 0.f;
  }
  __syncthreads();
  const int ocl = t & 31, pxl = (t >> 5) * 8;
  float acc[4][8];
#pragma unroll
  for (int i = 0; i < 4; ++i)
#pragma unroll
    for (int j = 0; j < 8; ++j) acc[i][j] = 0.f;
  for (int k = 0; k < 30; ++k) {
    float wv[4], ev[8];
#pragma unroll
    for (int i = 0; i < 4; ++i) wv[i] = w1s[ocl + 32 * i][k];
#pragma unroll
    for (int j = 0; j < 8; ++j) ev[j] = es[pxl + j][k];
#pragma unroll
    for (int i = 0; i < 4; ++i)
#pragma unroll
      for (int j = 0; j < 8; ++j) acc[i][j] += wv[i] * ev[j];
  }
#pragma unroll
  for (int i = 0; i < 4; ++i) {
    int oc = oc0 + ocl + 32 * i;
    if (oc >= 576) continue;
    float bv = (oc < 540) ? b1[oc] : 0.f;
#pragma unroll
    for (int j = 0; j < 8; ++j) {
      int px = px0 + pxl + j;
      float v = (oc < 540) ? fmaxf(acc[i][j] + bv, 0.f) : 0.f;
      hbf[(size_t)px * K2 + oc] = f2bf(v);
    }
  }
}

// ---------------- MFMA GEMM: MODE0 = w2 matmul (tanh), MODE1 = 3x3 conv (gate) ----------------
template <int MODE>
__global__ __launch_bounds__(256) void mfma_gemm_kernel(
    const u16* __restrict__ A, const u16* __restrict__ Bm,
    const float* __restrict__ bias, const float* __restrict__ tclip,
    float* __restrict__ marr, u16* __restrict__ git, float* __restrict__ out)
{
  constexpr int KC = (MODE == 1) ? 153 : 9;
  constexpr int BSTRIDE = (MODE == 1) ? KCONV : K2;
  __shared__ u16 smem[16384];                 // As 16KB + Bs 16KB
  u16* As = smem;
  u16* Bs = smem + 8192;
  const int t = threadIdx.x;
  const int lane = t & 63, wave = t >> 6;
  const int wm = wave & 1, wn = wave >> 1;
  const int px0 = blockIdx.x * 128, oc0 = blockIdx.y * 128;

  const u16* aSrc[4];
  const u16* bSrc[4];
  int dstOff[4];
#pragma unroll
  for (int r = 0; r < 4; ++r) {
    int slot = r * 256 + t;
    int row = slot >> 3;
    int gs = ((slot ^ row) & 7) << 3;         // XOR-swizzled 16B group
    if constexpr (MODE == 0) {
      aSrc[r] = A + (size_t)(px0 + row) * K2 + gs;
    } else {
      int px = px0 + row;
      int n = px / 196, q = px - n * 196;
      int y = q / 14, x = q - y * 14;
      aSrc[r] = A + (size_t)((n * 16 + y) * 16 + x) * CIPAD + gs;
    }
    bSrc[r] = Bm + (size_t)(oc0 + row) * BSTRIDE + gs;
    dstOff[r] = (r * 256 + wave * 64) * 8;    // wave-uniform LDS base (u16 units)
  }

  const int tx = lane & 15, quad = lane >> 4, l7 = lane & 7;
  int rowA[4], rowB[4];
#pragma unroll
  for (int i = 0; i < 4; ++i) {
    rowA[i] = (wm * 64 + i * 16 + tx) * 64;
    rowB[i] = (wn * 64 + i * 16 + tx) * 64;
  }

  f32x4 acc[4][4];
#pragma unroll
  for (int i = 0; i < 4; ++i)
#pragma unroll
    for (int j = 0; j < 4; ++j) acc[i][j] = (f32x4){0.f, 0.f, 0.f, 0.f};

  for (int kc = 0; kc < KC; ++kc) {
    int boff = kc * 64;
    int aoff;
    if constexpr (MODE == 1) {
      int tap = kc / 17;
      int cib = (kc - tap * 17) * 64;
      int ky = tap / 3, kx = tap - ky * 3;
      aoff = (ky * 16 + kx) * CIPAD + cib;
    } else aoff = boff;
#pragma unroll
    for (int r = 0; r < 4; ++r) cp16(aSrc[r] + aoff, As + dstOff[r]);
#pragma unroll
    for (int r = 0; r < 4; ++r) cp16(bSrc[r] + boff, Bs + dstOff[r]);
    __syncthreads();
#pragma unroll
    for (int ks = 0; ks < 2; ++ks) {
      int goff = (((ks * 4 + quad) ^ l7) << 3);
      bf16x8 af[4], bfr[4];
#pragma unroll
      for (int i = 0; i < 4; ++i) af[i] = *reinterpret_cast<const bf16x8*>(As + rowA[i] + goff);
#pragma unroll
      for (int i = 0; i < 4; ++i) bfr[i] = *reinterpret_cast<const bf16x8*>(Bs + rowB[i] + goff);
#pragma unroll
      for (int i = 0; i < 4; ++i)
#pragma unroll
        for (int j = 0; j < 4; ++j)
          acc[i][j] = __builtin_amdgcn_mfma_f32_16x16x32_bf16(af[i], bfr[j], acc[i][j], 0, 0, 0);
    }
    __syncthreads();
  }

#pragma unroll
  for (int j = 0; j < 4; ++j) {
    int oc = oc0 + wn * 64 + j * 16 + tx;
    if (oc >= 540) continue;
    float bv = bias[oc];
#pragma unroll
    for (int i = 0; i < 4; ++i) {
      f32x4 v = acc[i][j];
#pragma unroll
      for (int r = 0; r < 4; ++r) {
        int px = px0 + wm * 64 + i * 16 + quad * 4 + r;
        int n = px / 196, q = px - n * 196;
        int idx = (n * 540 + oc) * 196 + q;
        if constexpr (MODE == 0) {
          float val = tanhf(v[r] + bv);
          marr[idx] = val;
          int y = q / 14, x = q - y * 14;
          git[((n * 16 + 1 + y) * 16 + 1 + x) * CIPAD + 540 + oc] = f2bf(val);
        } else {
          float gv = v[r] + bv;
          float gamma = 1.f / (1.f + expf(-gv));
          out[idx] = tclip[idx] + gamma * marr[idx];
        }
      }
    }
  }
}

// ---------------- launcher ----------------
extern "C" void kernel_launch(void* const* d_in, const int* in_sizes, int n_in,
                              void* d_out, int out_size, void* d_ws, size_t ws_size,
                              hipStream_t stream)
{
  const float* frames = (const float*)d_in[0];
  const float* t_clip = (const float*)d_in[1];
  const float* w1 = (const float*)d_in[2];
  const float* b1 = (const float*)d_in[3];
  const float* w2 = (const float*)d_in[4];
  const float* b2 = (const float*)d_in[5];
  const float* wg = (const float*)d_in[6];
  const float* bg = (const float*)d_in[7];
  float* out = (float*)d_out;
  char* ws = (char*)d_ws;

  float* A1 = (float*)(ws + OFF_A1);
  float* A2 = (float*)(ws + OFF_A2);
  float* A3 = (float*)(ws + OFF_A3);
  int* HIST = (int*)(ws + OFF_HIST);
  float* SUMS = (float*)(ws + OFF_SUMS);
  float* INVS = (float*)(ws + OFF_INVS);
  float* EPIX = (float*)(ws + OFF_EPIX);
  u16* HBF = (u16*)(ws + OFF_HBF);
  u16* GIT = (u16*)(ws + OFF_GIT);
  u16* WGB = (u16*)(ws + OFF_WGB);
  u16* W2B = (u16*)(ws + OFF_W2B);
  float* MARR = (float*)(ws + OFF_MARR);

  // zero histograms+sums and the padded gi tensor (ws is poisoned each call)
  hipMemsetAsync(ws + OFF_HIST, 0, SZ_HIST + 768, stream);
  hipMemsetAsync(ws + OFF_GIT, 0, SZ_GIT, stream);

  // weight packs + t_clip -> gi (independent of SWT chain)
  pack_wg_kernel<<<24480, 256, 0, stream>>>(wg, WGB);
  pack_w2_kernel<<<1440, 256, 0, stream>>>(w2, W2B);
  fill_git_kernel<<<26460, 256, 0, stream>>>(t_clip, GIT);

  // SWT cascade + histograms
  swt_kernel<<<768, 256, 0, stream>>>(frames, A1, HIST + 0 * PLANES * BINS, SUMS, 1, 0);
  swt_kernel<<<768, 256, 0, stream>>>(A1, A2, HIST + 3 * PLANES * BINS, SUMS, 2, 0);
  swt_kernel<<<768, 256, 0, stream>>>(A2, A3, HIST + 6 * PLANES * BINS, SUMS, 4, 1);
  ll_hist_kernel<<<768, 256, 0, stream>>>(A3, SUMS, HIST + 9 * PLANES * BINS);
  quant_kernel<<<1920, 256, 0, stream>>>(HIST, INVS);
  pool_kernel<<<768, 256, 0, stream>>>(frames, A1, A2, A3, SUMS, INVS, EPIX);

  // MLP + gated conv
  gemm1_kernel<<<dim3(196, 5), 256, 0, stream>>>(EPIX, w1, b1, HBF);
  mfma_gemm_kernel<0><<<dim3(98, 5), 256, 0, stream>>>(HBF, W2B, b2, nullptr, MARR, GIT, nullptr);
  mfma_gemm_kernel<1><<<dim3(98, 5), 256, 0, stream>>>(GIT, WGB, bg, t_clip, MARR, nullptr, out);
}

// Round 2
// 733.263 us; speedup vs baseline: 1.0806x; 1.0806x over previous
//
#include <hip/hip_runtime.h>

typedef unsigned short u16;
typedef unsigned int u32;
typedef __bf16 bf16x8 __attribute__((ext_vector_type(8)));
typedef float f32x4 __attribute__((ext_vector_type(4)));

// ---------------- problem constants ----------------
constexpr int NB = 64, CH3 = 3;
constexpr int PLANES = NB * CH3;          // 192
constexpr int PPIX = 224 * 224;           // 50176 per plane
constexpr int PP = 196;                   // 14x14 pixels per image
constexpr int NPX = NB * PP;              // 12544
constexpr int K2 = 576;                   // padded K for w2 GEMM
constexpr int CIPAD = 1088;               // 1080 padded to 17*64
constexpr int KCONV = 9 * CIPAD;          // 9792 = 153*64
constexpr int BINS = 256;                 // clamped exponent+3-mantissa bins
constexpr int BIN0 = 896;                 // (bits>>20) offset: exp 112 (2^-15)
constexpr int RANK1 = 49674;              // order stats for q=0.99 over 50176
constexpr int RANK2 = 49675;

// ---------------- workspace layout (bytes) ----------------
constexpr size_t SZ_PLANE = (size_t)PLANES * PPIX * 4;        // 38,535,168
constexpr size_t OFF_A1   = 0;
constexpr size_t OFF_A2   = OFF_A1 + SZ_PLANE;
constexpr size_t OFF_HIST = OFF_A2 + SZ_PLANE;
constexpr size_t SZ_HIST  = (size_t)10 * PLANES * BINS * 4;   // 1,966,080
constexpr size_t OFF_SUMS = OFF_HIST + SZ_HIST;               // 192 f32
constexpr size_t OFF_INVS = OFF_SUMS + 768;                   // 1920 f32
constexpr size_t OFF_BSUM = OFF_INVS + 7680;                  // [10][192][196] f32
constexpr size_t SZ_BSUM  = (size_t)10 * PLANES * PP * 4;
constexpr size_t OFF_EPIX = OFF_BSUM + SZ_BSUM;               // NPX*32 f32
constexpr size_t OFF_HBF  = OFF_EPIX + (size_t)NPX * 32 * 4;  // NPX*576 bf16
constexpr size_t OFF_GIT  = OFF_HBF + (size_t)NPX * K2 * 2;   // 64*256*1088 bf16
constexpr size_t SZ_GIT   = (size_t)NB * 256 * CIPAD * 2;     // 35,651,584
constexpr size_t OFF_WGB  = OFF_GIT + SZ_GIT;                 // 640*9792 bf16
constexpr size_t OFF_W2B  = OFF_WGB + (size_t)640 * KCONV * 2;
constexpr size_t OFF_MARR = OFF_W2B + (size_t)640 * K2 * 2;   // NB*540*196 f32

__device__ __forceinline__ u16 f2bf(float x) {
  union { float f; u32 u; } c; c.f = x;
  u32 r = c.u + 0x7FFFu + ((c.u >> 16) & 1u);
  return (u16)(r >> 16);
}

__device__ __forceinline__ float wred64(float v) {
  v += __shfl_down(v, 32, 64); v += __shfl_down(v, 16, 64);
  v += __shfl_down(v, 8, 64);  v += __shfl_down(v, 4, 64);
  v += __shfl_down(v, 2, 64);  v += __shfl_down(v, 1, 64);
  return v;
}

__device__ __forceinline__ float gred16(float v) {
  v += __shfl_down(v, 8, 16); v += __shfl_down(v, 4, 16);
  v += __shfl_down(v, 2, 16); v += __shfl_down(v, 1, 16);
  return v;
}

__device__ __forceinline__ int hbin(float v) {
  int b = (int)(__float_as_uint(fabsf(v)) >> 20) - BIN0;
  return min(max(b, 0), BINS - 1);
}

__device__ __forceinline__ void cp16(const void* g, void* l) {
  __builtin_amdgcn_global_load_lds((const __attribute__((address_space(1))) u32*)g,
                                   (__attribute__((address_space(3))) u32*)l, 16, 0, 0);
}

// ---------------- SWT level + fused histograms + fused 16x16 pooling ----------------
// block = (rowband rb, plane); computes 16 rows x 224 cols of level-LEVEL bands.
// Accumulates: per-cell sums of cH,cV,cD (and cA at last level), 256-bin |.|
// histograms (8 LDS replicas), plane sum (level 1 only; mean(a3)=8*mean(frames)).
template <int LEVEL>
__global__ __launch_bounds__(256) void swt2_kernel(const float* __restrict__ src,
    float* __restrict__ dst, int* __restrict__ hist, float* __restrict__ sums,
    float* __restrict__ bsum)
{
  constexpr int d = 1 << (LEVEL - 1);
  constexpr bool LAST = (LEVEL == 3);
  constexpr int NH = LAST ? 4 : 3;
  __shared__ float rows[(16 + d) * 224];
  __shared__ int lh[8 * NH * BINS];
  __shared__ float csum[14 * NH];
  __shared__ float wsum[4];
  const int t = threadIdx.x;
  const int rb = blockIdx.x, plane = blockIdx.y;
  const float* Pp = src + (size_t)plane * PPIX;

  for (int i = t; i < (16 + d) * 224; i += 256) {
    int r = i / 224, c = i - r * 224;
    int gr = rb * 16 + r; if (gr >= 224) gr -= 224;
    rows[i] = Pp[gr * 224 + c];
  }
  for (int i = t; i < 8 * NH * BINS; i += 256) lh[i] = 0;
  __syncthreads();

  float mu = 0.f;
  if (LAST) mu = sums[plane] * (8.f / 50176.f);
  float sH = 0.f, sV = 0.f, sD = 0.f, sA = 0.f, ps = 0.f;
  if (t < 224) {
    int c2 = t + d; if (c2 >= 224) c2 -= 224;
    const int rep = t >> 5;
    for (int r = 0; r < 16; ++r) {
      float p00 = rows[r * 224 + t], p01 = rows[r * 224 + c2];
      float p10 = rows[(r + d) * 224 + t], p11 = rows[(r + d) * 224 + c2];
      float s0 = p00 + p01, s1 = p10 + p11, d0 = p00 - p01, d1 = p10 - p11;
      float cA = (s0 + s1) * 0.5f, cH = (s0 - s1) * 0.5f;
      float cV = (d0 + d1) * 0.5f, cD = (d0 - d1) * 0.5f;
      if (!LAST) dst[(size_t)plane * PPIX + (rb * 16 + r) * 224 + t] = cA;
      atomicAdd(&lh[(rep * NH + 0) * BINS + hbin(cH)], 1);
      atomicAdd(&lh[(rep * NH + 1) * BINS + hbin(cV)], 1);
      atomicAdd(&lh[(rep * NH + 2) * BINS + hbin(cD)], 1);
      if (LAST) atomicAdd(&lh[(rep * NH + 3) * BINS + hbin(cA - mu)], 1);
      sH += cH; sV += cV; sD += cD;
      if (LAST) sA += cA;
      if (LEVEL == 1) ps += p00;
    }
  }
  sH = gred16(sH); sV = gred16(sV); sD = gred16(sD);
  if (LAST) sA = gred16(sA);
  if (t < 224 && (t & 15) == 0) {
    int cell = t >> 4;
    csum[cell * NH + 0] = sH; csum[cell * NH + 1] = sV; csum[cell * NH + 2] = sD;
    if (LAST) csum[cell * NH + 3] = sA;
  }
  if (LEVEL == 1) {
    ps = wred64(ps);
    if ((t & 63) == 0) wsum[t >> 6] = ps;
  }
  __syncthreads();
  if (LEVEL == 1 && t == 0) atomicAdd(&sums[plane], wsum[0] + wsum[1] + wsum[2] + wsum[3]);
  for (int i = t; i < NH * BINS; i += 256) {
    int band = i >> 8, bin = i & (BINS - 1);
    int v = 0;
#pragma unroll
    for (int rp = 0; rp < 8; ++rp) v += lh[(rp * NH + band) * BINS + bin];
    if (v) {
      int bg = (band < 3) ? (3 * (LEVEL - 1) + band) : 9;
      atomicAdd(&hist[((size_t)bg * PLANES + plane) * BINS + bin], v);
    }
  }
  if (t < 14 * NH) {
    int cell = t / NH, band = t - cell * NH;
    int bg = (band < 3) ? (3 * (LEVEL - 1) + band) : 9;
    bsum[((size_t)bg * PLANES + plane) * PP + rb * 14 + cell] = csum[cell * NH + band];
  }
}

// ---------------- quantile from 256-bin histogram ----------------
__global__ __launch_bounds__(256) void quant_kernel(const int* __restrict__ hist,
    float* __restrict__ invs)
{
  const int g = blockIdx.x;
  __shared__ int h[BINS];
  const int t = threadIdx.x;
  h[t] = hist[(size_t)g * BINS + t];
  __syncthreads();
  if (t == 0) {
    float v[2] = {0.f, 0.f};
    int cum = 0, target = 0;
    for (int b = 0; b < BINS && target < 2; ++b) {
      int c = h[b];
      while (target < 2) {
        int rank = target ? RANK2 : RANK1;
        if (cum + c >= rank) {
          float lo = __uint_as_float((u32)(b + BIN0) << 20);
          float hi = __uint_as_float((u32)(b + BIN0 + 1) << 20);
          float fr = ((float)(rank - cum) - 0.5f) / (float)c;
          fr = fminf(fmaxf(fr, 0.f), 1.f);
          v[target] = lo + (hi - lo) * fr;
          ++target;
        } else break;
      }
      cum += c;
    }
    float s = 0.75f * v[0] + 0.25f * v[1];
    invs[g] = 1.f / (s + 1e-4f);
  }
}

// ---------------- e_pix assembly from cell sums ----------------
__global__ __launch_bounds__(256) void epix_kernel(const float* __restrict__ bsum,
    const float* __restrict__ sums, const float* __restrict__ invs, float* __restrict__ epix)
{
  int tid = blockIdx.x * 256 + threadIdx.x;     // < NPX*32
  int ch = tid & 31, px = tid >> 5;
  int n = px / PP, q = px - n * PP;
  float val = 0.f;
  if (ch < 27) {
    int bg = ch / 3, c = ch - bg * 3;
    int plane = n * 3 + c;
    val = bsum[((size_t)bg * PLANES + plane) * PP + q] * (1.f / 256.f) * invs[bg * PLANES + plane];
  } else if (ch < 30) {
    int c = ch - 27, plane = n * 3 + c;
    float mu = sums[plane] * (8.f / 50176.f);
    val = (bsum[((size_t)9 * PLANES + plane) * PP + q] * (1.f / 256.f) - mu) * invs[9 * PLANES + plane];
  }
  epix[tid] = val;
}

// ---------------- weight packing (tap-fastest K order: k = (cib*9+tap)*64+i) --------
__global__ __launch_bounds__(256) void pack_wg_kernel(const float* __restrict__ wg,
    u16* __restrict__ wgb)
{
  int tid = blockIdx.x * 256 + threadIdx.x;   // < 640*9792
  int oc = tid / KCONV, k = tid - oc * KCONV;
  int kc = k >> 6, i = k & 63;
  int cib = kc / 9, tap = kc - cib * 9;
  int ci = cib * 64 + i;
  float v = (oc < 540 && ci < 1080) ? wg[(oc * 1080 + ci) * 9 + tap] : 0.f;
  wgb[tid] = f2bf(v);
}

__global__ __launch_bounds__(256) void pack_w2_kernel(const float* __restrict__ w2,
    u16* __restrict__ w2b)
{
  int tid = blockIdx.x * 256 + threadIdx.x;   // < 640*576
  int oc = tid / K2, cc = tid - oc * K2;
  float v = (oc < 540 && cc < 540) ? w2[oc * 540 + cc] : 0.f;
  w2b[tid] = f2bf(v);
}

// ---------------- t_clip -> padded channel-last gi tensor (LDS transpose) ----------
__global__ __launch_bounds__(256) void fill_git_kernel(const float* __restrict__ tclip,
    u16* __restrict__ git)
{
  __shared__ float tile[64][65];
  const int n = blockIdx.z, ct = blockIdx.y, qt = blockIdx.x;
  const int t = threadIdx.x, tr = t >> 6, tc = t & 63;
#pragma unroll 4
  for (int i = 0; i < 16; ++i) {
    int ci = ct * 64 + i * 4 + tr, q = qt * 64 + tc;
    float v = (ci < 540 && q < 196) ? tclip[((size_t)n * 540 + ci) * 196 + q] : 0.f;
    tile[i * 4 + tr][tc] = v;
  }
  __syncthreads();
#pragma unroll 4
  for (int i = 0; i < 16; ++i) {
    int q = qt * 64 + i * 4 + tr, ci = ct * 64 + tc;
    if (q < 196 && ci < 540) {
      int y = q / 14, x = q - y * 14;
      git[(((size_t)n * 16 + 1 + y) * 16 + 1 + x) * CIPAD + ci] = f2bf(tile[tc][i * 4 + tr]);
    }
  }
}

// ---------------- GEMM1: h = relu(w1 @ e_pix + b1) -> bf16 [px][576] ----------------
__global__ __launch_bounds__(256) void gemm1_kernel(const float* __restrict__ epix,
    const float* __restrict__ w1, const float* __restrict__ b1, u16* __restrict__ hbf)
{
  __shared__ float es[64][33];
  __shared__ float w1s[128][33];
  const int t = threadIdx.x;
  const int px0 = blockIdx.x * 64, oc0 = blockIdx.y * 128;
  for (int i = t; i < 64 * 32; i += 256) { int r = i >> 5, cc = i & 31; es[r][cc] = epix[(size_t)(px0 + r) * 32 + cc]; }
  for (int i = t; i < 128 * 32; i += 256) {
    int r = i >> 5, cc = i & 31; int oc = oc0 + r;
    w1s[r][cc] = (oc < 540 && cc < 30) ? w1[oc * 30 + cc] : 0.f;
  }
  __syncthreads();
  const int ocl = t & 31, pxl = (t >> 5) * 8;
  float acc[4][8];
#pragma unroll
  for (int i = 0; i < 4; ++i)
#pragma unroll
    for (int j = 0; j < 8; ++j) acc[i][j] = 0.f;
  for (int k = 0; k < 30; ++k) {
    float wv[4], ev[8];
#pragma unroll
    for (int i = 0; i < 4; ++i) wv[i] = w1s[ocl + 32 * i][k];
#pragma unroll
    for (int j = 0; j < 8; ++j) ev[j] = es[pxl + j][k];
#pragma unroll
    for (int i = 0; i < 4; ++i)
#pragma unroll
      for (int j = 0; j < 8; ++j) acc[i][j] += wv[i] * ev[j];
  }
#pragma unroll
  for (int i = 0; i < 4; ++i) {
    int oc = oc0 + ocl + 32 * i;
    if (oc >= 576) continue;
    float bv = (oc < 540) ? b1[oc] : 0.f;
#pragma unroll
    for (int j = 0; j < 8; ++j) {
      int px = px0 + pxl + j;
      float v = (oc < 540) ? fmaxf(acc[i][j] + bv, 0.f) : 0.f;
      hbf[(size_t)px * K2 + oc] = f2bf(v);
    }
  }
}

// ---------------- MFMA GEMM: MODE0 = w2 matmul (tanh), MODE1 = 3x3 conv (gate) ------
template <int MODE>
__global__ __launch_bounds__(256) void mfma_gemm_kernel(
    const u16* __restrict__ A, const u16* __restrict__ Bm,
    const float* __restrict__ bias, const float* __restrict__ tclip,
    float* __restrict__ marr, u16* __restrict__ git, float* __restrict__ out)
{
  constexpr int KC = (MODE == 1) ? 153 : 9;
  constexpr int BSTRIDE = (MODE == 1) ? KCONV : K2;
  __shared__ u16 smem[16384];                 // As 16KB + Bs 16KB
  u16* As = smem;
  u16* Bs = smem + 8192;
  const int t = threadIdx.x;
  const int lane = t & 63, wave = t >> 6;
  const int wm = wave & 1, wn = wave >> 1;

  int px0, oc0;
  if constexpr (MODE == 1) {
    // XCD-aware swizzle (id%8 = XCD assumed): all 5 oc-tiles of one px-tile
    // land on the same XCD -> A slab shared 5-ways in that XCD's L2.
    int bid = blockIdx.x;
    int xcd = bid & 7, slot = bid >> 3;
    int by = slot % 5, bxi = slot / 5;
    int bx = xcd + 8 * bxi;
    if (bx >= 98) return;
    px0 = bx * 128; oc0 = by * 128;
  } else {
    px0 = blockIdx.x * 128; oc0 = blockIdx.y * 128;
  }

  const u16* aSrc[4];
  const u16* bSrc[4];
  int dstOff[4];
#pragma unroll
  for (int r = 0; r < 4; ++r) {
    int slot = r * 256 + t;
    int row = slot >> 3;
    int gs = ((slot ^ row) & 7) << 3;         // XOR-swizzled 16B group
    if constexpr (MODE == 0) {
      aSrc[r] = A + (size_t)(px0 + row) * K2 + gs;
    } else {
      int px = px0 + row;
      int n = px / 196, q = px - n * 196;
      int y = q / 14, x = q - y * 14;
      aSrc[r] = A + (size_t)((n * 16 + y) * 16 + x) * CIPAD + gs;
    }
    bSrc[r] = Bm + (size_t)(oc0 + row) * BSTRIDE + gs;
    dstOff[r] = (r * 256 + wave * 64) * 8;    // wave-uniform LDS base (u16 units)
  }

  const int tx = lane & 15, quad = lane >> 4, l7 = lane & 7;
  int rowA[4], rowB[4];
#pragma unroll
  for (int i = 0; i < 4; ++i) {
    rowA[i] = (wm * 64 + i * 16 + tx) * 64;
    rowB[i] = (wn * 64 + i * 16 + tx) * 64;
  }

  f32x4 acc[4][4];
#pragma unroll
  for (int i = 0; i < 4; ++i)
#pragma unroll
    for (int j = 0; j < 4; ++j) acc[i][j] = (f32x4){0.f, 0.f, 0.f, 0.f};

  for (int kc = 0; kc < KC; ++kc) {
    int boff = kc * 64;
    int aoff;
    if constexpr (MODE == 1) {
      // tap-fastest K order: 9 consecutive stages reuse the same A ci-window
      int cib = kc / 9, tap = kc - cib * 9;
      int ky = tap / 3, kx = tap - ky * 3;
      aoff = (ky * 16 + kx) * CIPAD + cib * 64;
    } else aoff = boff;
#pragma unroll
    for (int r = 0; r < 4; ++r) cp16(aSrc[r] + aoff, As + dstOff[r]);
#pragma unroll
    for (int r = 0; r < 4; ++r) cp16(bSrc[r] + boff, Bs + dstOff[r]);
    __syncthreads();
#pragma unroll
    for (int ks = 0; ks < 2; ++ks) {
      int goff = (((ks * 4 + quad) ^ l7) << 3);
      bf16x8 af[4], bfr[4];
#pragma unroll
      for (int i = 0; i < 4; ++i) af[i] = *reinterpret_cast<const bf16x8*>(As + rowA[i] + goff);
#pragma unroll
      for (int i = 0; i < 4; ++i) bfr[i] = *reinterpret_cast<const bf16x8*>(Bs + rowB[i] + goff);
#pragma unroll
      for (int i = 0; i < 4; ++i)
#pragma unroll
        for (int j = 0; j < 4; ++j)
          acc[i][j] = __builtin_amdgcn_mfma_f32_16x16x32_bf16(af[i], bfr[j], acc[i][j], 0, 0, 0);
    }
    __syncthreads();
  }

#pragma unroll
  for (int j = 0; j < 4; ++j) {
    int oc = oc0 + wn * 64 + j * 16 + tx;
    if (oc >= 540) continue;
    float bv = bias[oc];
#pragma unroll
    for (int i = 0; i < 4; ++i) {
      f32x4 v = acc[i][j];
#pragma unroll
      for (int r = 0; r < 4; ++r) {
        int px = px0 + wm * 64 + i * 16 + quad * 4 + r;
        int n = px / 196, q = px - n * 196;
        int idx = (n * 540 + oc) * 196 + q;
        if constexpr (MODE == 0) {
          float val = tanhf(v[r] + bv);
          marr[idx] = val;
          int y = q / 14, x = q - y * 14;
          git[((n * 16 + 1 + y) * 16 + 1 + x) * CIPAD + 540 + oc] = f2bf(val);
        } else {
          float gv = v[r] + bv;
          float gamma = 1.f / (1.f + expf(-gv));
          out[idx] = tclip[idx] + gamma * marr[idx];
        }
      }
    }
  }
}

// ---------------- launcher ----------------
extern "C" void kernel_launch(void* const* d_in, const int* in_sizes, int n_in,
                              void* d_out, int out_size, void* d_ws, size_t ws_size,
                              hipStream_t stream)
{
  const float* frames = (const float*)d_in[0];
  const float* t_clip = (const float*)d_in[1];
  const float* w1 = (const float*)d_in[2];
  const float* b1 = (const float*)d_in[3];
  const float* w2 = (const float*)d_in[4];
  const float* b2 = (const float*)d_in[5];
  const float* wg = (const float*)d_in[6];
  const float* bg = (const float*)d_in[7];
  float* out = (float*)d_out;
  char* ws = (char*)d_ws;

  float* A1 = (float*)(ws + OFF_A1);
  float* A2 = (float*)(ws + OFF_A2);
  int* HIST = (int*)(ws + OFF_HIST);
  float* SUMS = (float*)(ws + OFF_SUMS);
  float* INVS = (float*)(ws + OFF_INVS);
  float* BSUM = (float*)(ws + OFF_BSUM);
  float* EPIX = (float*)(ws + OFF_EPIX);
  u16* HBF = (u16*)(ws + OFF_HBF);
  u16* GIT = (u16*)(ws + OFF_GIT);
  u16* WGB = (u16*)(ws + OFF_WGB);
  u16* W2B = (u16*)(ws + OFF_W2B);
  float* MARR = (float*)(ws + OFF_MARR);

  // zero hist+sums and the padded gi tensor (ws is poisoned each call)
  hipMemsetAsync(ws + OFF_HIST, 0, SZ_HIST + 768, stream);
  hipMemsetAsync(ws + OFF_GIT, 0, SZ_GIT, stream);

  // weight packs + t_clip -> gi (independent of SWT chain)
  pack_wg_kernel<<<24480, 256, 0, stream>>>(wg, WGB);
  pack_w2_kernel<<<1440, 256, 0, stream>>>(w2, W2B);
  fill_git_kernel<<<dim3(4, 9, 64), 256, 0, stream>>>(t_clip, GIT);

  // SWT cascade with fused histograms + pooling (A3 never materialized)
  swt2_kernel<1><<<dim3(14, PLANES), 256, 0, stream>>>(frames, A1, HIST, SUMS, BSUM);
  swt2_kernel<2><<<dim3(14, PLANES), 256, 0, stream>>>(A1, A2, HIST, SUMS, BSUM);
  swt2_kernel<3><<<dim3(14, PLANES), 256, 0, stream>>>(A2, nullptr, HIST, SUMS, BSUM);
  quant_kernel<<<1920, 256, 0, stream>>>(HIST, INVS);
  epix_kernel<<<1568, 256, 0, stream>>>(BSUM, SUMS, INVS, EPIX);

  // MLP + gated conv
  gemm1_kernel<<<dim3(196, 5), 256, 0, stream>>>(EPIX, w1, b1, HBF);
  mfma_gemm_kernel<0><<<dim3(98, 5), 256, 0, stream>>>(HBF, W2B, b2, nullptr, MARR, GIT, nullptr);
  mfma_gemm_kernel<1><<<520, 256, 0, stream>>>(GIT, WGB, bg, t_clip, MARR, nullptr, out);
}

// Round 3
// 662.450 us; speedup vs baseline: 1.1961x; 1.1069x over previous
//
#include <hip/hip_runtime.h>

typedef unsigned short u16;
typedef unsigned int u32;
typedef __bf16 bf16x8 __attribute__((ext_vector_type(8)));
typedef float f32x4 __attribute__((ext_vector_type(4)));

// ---------------- problem constants ----------------
constexpr int NB = 64, CH3 = 3;
constexpr int PLANES = NB * CH3;          // 192
constexpr int PPIX = 224 * 224;           // 50176 per plane
constexpr int PP = 196;                   // 14x14 pixels per image
constexpr int NPX = NB * PP;              // 12544
constexpr int K2 = 576;                   // padded K for w2 GEMM
constexpr int CIPAD = 1088;               // 1080 padded to 17*64
constexpr int KCONV = 9 * CIPAD;          // 9792 = 153*64
constexpr int BINS = 256;                 // clamped exponent+3-mantissa bins
constexpr int BIN0 = 896;                 // (bits>>20) offset
constexpr int RANK1 = 49674;              // order stats for q=0.99 over 50176
constexpr int RANK2 = 49675;

// ---------------- workspace layout (bytes) ----------------
constexpr size_t SZ_PLANE = (size_t)PLANES * PPIX * 4;        // 38,535,168
constexpr size_t OFF_A1   = 0;
constexpr size_t OFF_A2   = OFF_A1 + SZ_PLANE;
constexpr size_t OFF_HIST = OFF_A2 + SZ_PLANE;
constexpr size_t SZ_HIST  = (size_t)10 * PLANES * BINS * 4;   // 1,966,080
constexpr size_t OFF_SUMS = OFF_HIST + SZ_HIST;               // 192 f32
constexpr size_t OFF_INVS = OFF_SUMS + 768;                   // 1920 f32
constexpr size_t OFF_BSUM = OFF_INVS + 7680;                  // [10][192][196] f32
constexpr size_t SZ_BSUM  = (size_t)10 * PLANES * PP * 4;
constexpr size_t OFF_EPIX = OFF_BSUM + SZ_BSUM;               // NPX*32 f32
constexpr size_t OFF_HBF  = OFF_EPIX + (size_t)NPX * 32 * 4;  // NPX*576 bf16
constexpr size_t OFF_GIT  = OFF_HBF + (size_t)NPX * K2 * 2;   // 64*256*1088 bf16
constexpr size_t SZ_GIT   = (size_t)NB * 256 * CIPAD * 2;     // 35,651,584
constexpr size_t OFF_WGB  = OFF_GIT + SZ_GIT;                 // 640*9792 bf16
constexpr size_t OFF_W2B  = OFF_WGB + (size_t)640 * KCONV * 2;
constexpr size_t OFF_MARR = OFF_W2B + (size_t)640 * K2 * 2;   // NB*540*196 f32

__device__ __forceinline__ u16 f2bf(float x) {
  union { float f; u32 u; } c; c.f = x;
  u32 r = c.u + 0x7FFFu + ((c.u >> 16) & 1u);
  return (u16)(r >> 16);
}

__device__ __forceinline__ float wred64(float v) {
  v += __shfl_down(v, 32, 64); v += __shfl_down(v, 16, 64);
  v += __shfl_down(v, 8, 64);  v += __shfl_down(v, 4, 64);
  v += __shfl_down(v, 2, 64);  v += __shfl_down(v, 1, 64);
  return v;
}

__device__ __forceinline__ float gred16(float v) {
  v += __shfl_down(v, 8, 16); v += __shfl_down(v, 4, 16);
  v += __shfl_down(v, 2, 16); v += __shfl_down(v, 1, 16);
  return v;
}

__device__ __forceinline__ int hbin(float v) {
  int b = (int)(__float_as_uint(fabsf(v)) >> 20) - BIN0;
  return min(max(b, 0), BINS - 1);
}

__device__ __forceinline__ void cp16(const void* g, void* l) {
  __builtin_amdgcn_global_load_lds((const __attribute__((address_space(1))) u32*)g,
                                   (__attribute__((address_space(3))) u32*)l, 16, 0, 0);
}

// ---------------- SWT level + fused histograms + fused 16x16 pooling ----------------
// 14 halfword-packed histogram replicas (one per 16 lanes); max count per
// halfword = 16 threads * 16 rows = 256 < 65536, so no carry into neighbor.
template <int LEVEL>
__global__ __launch_bounds__(256) void swt2_kernel(const float* __restrict__ src,
    float* __restrict__ dst, int* __restrict__ hist, float* __restrict__ sums,
    float* __restrict__ bsum)
{
  constexpr int d = 1 << (LEVEL - 1);
  constexpr bool LAST = (LEVEL == 3);
  constexpr int NH = LAST ? 4 : 3;
  constexpr int NREP = 14;
  __shared__ float rows[(16 + d) * 224];
  __shared__ u32 lh[NREP * NH * 128];
  __shared__ float csum[14 * NH];
  __shared__ float wsum[4];
  const int t = threadIdx.x;
  const int rb = blockIdx.x, plane = blockIdx.y;
  const float* Pp = src + (size_t)plane * PPIX;

  for (int i = t; i < (16 + d) * 224; i += 256) {
    int r = i / 224, c = i - r * 224;
    int gr = rb * 16 + r; if (gr >= 224) gr -= 224;
    rows[i] = Pp[gr * 224 + c];
  }
  for (int i = t; i < NREP * NH * 128; i += 256) lh[i] = 0;
  __syncthreads();

  float mu = 0.f;
  if (LAST) mu = sums[plane] * (8.f / 50176.f);
  float sH = 0.f, sV = 0.f, sD = 0.f, sA = 0.f, ps = 0.f;
  if (t < 224) {
    int c2 = t + d; if (c2 >= 224) c2 -= 224;
    const int rep = t >> 4;
    u32* lhr = &lh[rep * NH * 128];
    for (int r = 0; r < 16; ++r) {
      float p00 = rows[r * 224 + t], p01 = rows[r * 224 + c2];
      float p10 = rows[(r + d) * 224 + t], p11 = rows[(r + d) * 224 + c2];
      float s0 = p00 + p01, s1 = p10 + p11, d0 = p00 - p01, d1 = p10 - p11;
      float cA = (s0 + s1) * 0.5f, cH = (s0 - s1) * 0.5f;
      float cV = (d0 + d1) * 0.5f, cD = (d0 - d1) * 0.5f;
      if (!LAST) dst[(size_t)plane * PPIX + (rb * 16 + r) * 224 + t] = cA;
      int bH = hbin(cH), bV = hbin(cV), bD = hbin(cD);
      atomicAdd(&lhr[0 * 128 + (bH >> 1)], 1u << ((bH & 1) * 16));
      atomicAdd(&lhr[1 * 128 + (bV >> 1)], 1u << ((bV & 1) * 16));
      atomicAdd(&lhr[2 * 128 + (bD >> 1)], 1u << ((bD & 1) * 16));
      if (LAST) {
        int bA = hbin(cA - mu);
        atomicAdd(&lhr[3 * 128 + (bA >> 1)], 1u << ((bA & 1) * 16));
      }
      sH += cH; sV += cV; sD += cD;
      if (LAST) sA += cA;
      if (LEVEL == 1) ps += p00;
    }
  }
  sH = gred16(sH); sV = gred16(sV); sD = gred16(sD);
  if (LAST) sA = gred16(sA);
  if (t < 224 && (t & 15) == 0) {
    int cell = t >> 4;
    csum[cell * NH + 0] = sH; csum[cell * NH + 1] = sV; csum[cell * NH + 2] = sD;
    if (LAST) csum[cell * NH + 3] = sA;
  }
  if (LEVEL == 1) {
    ps = wred64(ps);
    if ((t & 63) == 0) wsum[t >> 6] = ps;
  }
  __syncthreads();
  if (LEVEL == 1 && t == 0) atomicAdd(&sums[plane], wsum[0] + wsum[1] + wsum[2] + wsum[3]);
  for (int i = t; i < NH * 256; i += 256) {
    int band = i >> 8, b = i & 255;
    u32 acc = 0;
#pragma unroll
    for (int rp = 0; rp < NREP; ++rp)
      acc += (lh[(rp * NH + band) * 128 + (b >> 1)] >> ((b & 1) * 16)) & 0xFFFFu;
    if (acc) {
      int bg = (band < 3) ? (3 * (LEVEL - 1) + band) : 9;
      atomicAdd(&hist[((size_t)bg * PLANES + plane) * BINS + b], (int)acc);
    }
  }
  if (t < 14 * NH) {
    int cell = t / NH, band = t - cell * NH;
    int bg = (band < 3) ? (3 * (LEVEL - 1) + band) : 9;
    bsum[((size_t)bg * PLANES + plane) * PP + rb * 14 + cell] = csum[cell * NH + band];
  }
}

// ---------------- quantile from 256-bin histogram ----------------
__global__ __launch_bounds__(256) void quant_kernel(const int* __restrict__ hist,
    float* __restrict__ invs)
{
  const int g = blockIdx.x;
  __shared__ int h[BINS];
  const int t = threadIdx.x;
  h[t] = hist[(size_t)g * BINS + t];
  __syncthreads();
  if (t == 0) {
    float v[2] = {0.f, 0.f};
    int cum = 0, target = 0;
    for (int b = 0; b < BINS && target < 2; ++b) {
      int c = h[b];
      while (target < 2) {
        int rank = target ? RANK2 : RANK1;
        if (cum + c >= rank) {
          float lo = __uint_as_float((u32)(b + BIN0) << 20);
          float hi = __uint_as_float((u32)(b + BIN0 + 1) << 20);
          float fr = ((float)(rank - cum) - 0.5f) / (float)c;
          fr = fminf(fmaxf(fr, 0.f), 1.f);
          v[target] = lo + (hi - lo) * fr;
          ++target;
        } else break;
      }
      cum += c;
    }
    float s = 0.75f * v[0] + 0.25f * v[1];
    invs[g] = 1.f / (s + 1e-4f);
  }
}

// ---------------- e_pix assembly from cell sums ----------------
__global__ __launch_bounds__(256) void epix_kernel(const float* __restrict__ bsum,
    const float* __restrict__ sums, const float* __restrict__ invs, float* __restrict__ epix)
{
  int tid = blockIdx.x * 256 + threadIdx.x;     // < NPX*32
  int ch = tid & 31, px = tid >> 5;
  int n = px / PP, q = px - n * PP;
  float val = 0.f;
  if (ch < 27) {
    int bg = ch / 3, c = ch - bg * 3;
    int plane = n * 3 + c;
    val = bsum[((size_t)bg * PLANES + plane) * PP + q] * (1.f / 256.f) * invs[bg * PLANES + plane];
  } else if (ch < 30) {
    int c = ch - 27, plane = n * 3 + c;
    float mu = sums[plane] * (8.f / 50176.f);
    val = (bsum[((size_t)9 * PLANES + plane) * PP + q] * (1.f / 256.f) - mu) * invs[9 * PLANES + plane];
  }
  epix[tid] = val;
}

// ---------------- wg pack: per-oc LDS stage, coalesced read+write -----------------
// K order matches conv: k = (cib*9+tap)*64 + i, ci = cib*64+i
__global__ __launch_bounds__(256) void pack_wg_kernel(const float* __restrict__ wg,
    u16* __restrict__ wgb)
{
  __shared__ float w[9720];
  const int oc = blockIdx.x;     // 640
  const int t = threadIdx.x;
  if (oc < 540) {
    for (int i = t; i < 9720; i += 256) w[i] = wg[(size_t)oc * 9720 + i];
  }
  __syncthreads();
  for (int j = t; j < KCONV; j += 256) {
    int kc = j >> 6, i = j & 63;
    int cib = kc / 9, tap = kc - cib * 9;
    int ci = cib * 64 + i;
    float v = (oc < 540 && ci < 1080) ? w[ci * 9 + tap] : 0.f;
    wgb[(size_t)oc * KCONV + j] = f2bf(v);
  }
}

__global__ __launch_bounds__(256) void pack_w2_kernel(const float* __restrict__ w2,
    u16* __restrict__ w2b)
{
  int tid = blockIdx.x * 256 + threadIdx.x;   // < 640*576
  int oc = tid / K2, cc = tid - oc * K2;
  float v = (oc < 540 && cc < 540) ? w2[oc * 540 + cc] : 0.f;
  w2b[tid] = f2bf(v);
}

// ---------------- t_clip -> padded channel-last gi tensor (LDS transpose) ----------
__global__ __launch_bounds__(256) void fill_git_kernel(const float* __restrict__ tclip,
    u16* __restrict__ git)
{
  __shared__ float tile[64][65];
  const int n = blockIdx.z, ct = blockIdx.y, qt = blockIdx.x;
  const int t = threadIdx.x, tr = t >> 6, tc = t & 63;
#pragma unroll 4
  for (int i = 0; i < 16; ++i) {
    int ci = ct * 64 + i * 4 + tr, q = qt * 64 + tc;
    float v = (ci < 540 && q < 196) ? tclip[((size_t)n * 540 + ci) * 196 + q] : 0.f;
    tile[i * 4 + tr][tc] = v;
  }
  __syncthreads();
#pragma unroll 4
  for (int i = 0; i < 16; ++i) {
    int q = qt * 64 + i * 4 + tr, ci = ct * 64 + tc;
    if (q < 196 && ci < 540) {
      int y = q / 14, x = q - y * 14;
      git[(((size_t)n * 16 + 1 + y) * 16 + 1 + x) * CIPAD + ci] = f2bf(tile[tc][i * 4 + tr]);
    }
  }
}

// ---------------- GEMM1: h = relu(w1 @ e_pix + b1) -> bf16 [px][576] ----------------
__global__ __launch_bounds__(256) void gemm1_kernel(const float* __restrict__ epix,
    const float* __restrict__ w1, const float* __restrict__ b1, u16* __restrict__ hbf)
{
  __shared__ float es[64][33];
  __shared__ float w1s[128][33];
  const int t = threadIdx.x;
  const int px0 = blockIdx.x * 64, oc0 = blockIdx.y * 128;
  for (int i = t; i < 64 * 32; i += 256) { int r = i >> 5, cc = i & 31; es[r][cc] = epix[(size_t)(px0 + r) * 32 + cc]; }
  for (int i = t; i < 128 * 32; i += 256) {
    int r = i >> 5, cc = i & 31; int oc = oc0 + r;
    w1s[r][cc] = (oc < 540 && cc < 30) ? w1[oc * 30 + cc] : 0.f;
  }
  __syncthreads();
  const int ocl = t & 31, pxl = (t >> 5) * 8;
  float acc[4][8];
#pragma unroll
  for (int i = 0; i < 4; ++i)
#pragma unroll
    for (int j = 0; j < 8; ++j) acc[i][j] = 0.f;
  for (int k = 0; k < 30; ++k) {
    float wv[4], ev[8];
#pragma unroll
    for (int i = 0; i < 4; ++i) wv[i] = w1s[ocl + 32 * i][k];
#pragma unroll
    for (int j = 0; j < 8; ++j) ev[j] = es[pxl + j][k];
#pragma unroll
    for (int i = 0; i < 4; ++i)
#pragma unroll
      for (int j = 0; j < 8; ++j) acc[i][j] += wv[i] * ev[j];
  }
#pragma unroll
  for (int i = 0; i < 4; ++i) {
    int oc = oc0 + ocl + 32 * i;
    if (oc >= 576) continue;
    float bv = (oc < 540) ? b1[oc] : 0.f;
#pragma unroll
    for (int j = 0; j < 8; ++j) {
      int px = px0 + pxl + j;
      float v = (oc < 540) ? fmaxf(acc[i][j] + bv, 0.f) : 0.f;
      hbf[(size_t)px * K2 + oc] = f2bf(v);
    }
  }
}

// ---------------- MFMA GEMM, double-buffered LDS pipeline ----------------
// MODE0 = w2 matmul (tanh epilogue), MODE1 = 3x3 conv (sigmoid-gate epilogue)
template <int MODE>
__global__ __launch_bounds__(256) void mfma_gemm_kernel(
    const u16* __restrict__ A, const u16* __restrict__ Bm,
    const float* __restrict__ bias, const float* __restrict__ tclip,
    float* __restrict__ marr, u16* __restrict__ git, float* __restrict__ out)
{
  constexpr int KC = (MODE == 1) ? 153 : 9;
  constexpr int BSTRIDE = (MODE == 1) ? KCONV : K2;
  __shared__ u16 smem[2][16384];              // per buf: As 16KB + Bs 16KB
  const int t = threadIdx.x;
  const int lane = t & 63, wave = t >> 6;
  const int wm = wave & 1, wn = wave >> 1;

  int px0, oc0;
  if constexpr (MODE == 1) {
    int bid = blockIdx.x;
    int xcd = bid & 7, slot = bid >> 3;
    int by = slot % 5, bxi = slot / 5;
    int bx = xcd + 8 * bxi;
    if (bx >= 98) return;
    px0 = bx * 128; oc0 = by * 128;
  } else {
    px0 = blockIdx.x * 128; oc0 = blockIdx.y * 128;
  }

  const u16* aSrc[4];
  const u16* bSrc[4];
  int dstOff[4];
#pragma unroll
  for (int r = 0; r < 4; ++r) {
    int slot = r * 256 + t;
    int row = slot >> 3;
    int gs = ((slot ^ row) & 7) << 3;         // XOR-swizzled 16B group
    if constexpr (MODE == 0) {
      aSrc[r] = A + (size_t)(px0 + row) * K2 + gs;
    } else {
      int px = px0 + row;
      int n = px / 196, q = px - n * 196;
      int y = q / 14, x = q - y * 14;
      aSrc[r] = A + (size_t)((n * 16 + y) * 16 + x) * CIPAD + gs;
    }
    bSrc[r] = Bm + (size_t)(oc0 + row) * BSTRIDE + gs;
    dstOff[r] = (r * 256 + wave * 64) * 8;    // wave-uniform LDS base (u16 units)
  }

  auto stage = [&](int kc, int buf) {
    int boff = kc * 64;
    int aoff;
    if constexpr (MODE == 1) {
      int cib = kc / 9, tap = kc - cib * 9;   // tap-fastest: A window reused 9x
      int ky = tap / 3, kx = tap - ky * 3;
      aoff = (ky * 16 + kx) * CIPAD + cib * 64;
    } else aoff = boff;
    u16* As = &smem[buf][0];
    u16* Bs = &smem[buf][8192];
#pragma unroll
    for (int r = 0; r < 4; ++r) cp16(aSrc[r] + aoff, As + dstOff[r]);
#pragma unroll
    for (int r = 0; r < 4; ++r) cp16(bSrc[r] + boff, Bs + dstOff[r]);
  };

  const int tx = lane & 15, quad = lane >> 4, l7 = lane & 7;
  int rowA[4], rowB[4];
#pragma unroll
  for (int i = 0; i < 4; ++i) {
    rowA[i] = (wm * 64 + i * 16 + tx) * 64;
    rowB[i] = (wn * 64 + i * 16 + tx) * 64;
  }

  f32x4 acc[4][4];
#pragma unroll
  for (int i = 0; i < 4; ++i)
#pragma unroll
    for (int j = 0; j < 4; ++j) acc[i][j] = (f32x4){0.f, 0.f, 0.f, 0.f};

  stage(0, 0);
  for (int kc = 0; kc < KC; ++kc) {
    const int cur = kc & 1;
    __syncthreads();                          // buf[cur] staged (vmcnt drain here)
    if (kc + 1 < KC) stage(kc + 1, cur ^ 1);  // async prefetch overlaps MFMA below
    const u16* As = &smem[cur][0];
    const u16* Bs = &smem[cur][8192];
#pragma unroll
    for (int ks = 0; ks < 2; ++ks) {
      int goff = (((ks * 4 + quad) ^ l7) << 3);
      bf16x8 af[4], bfr[4];
#pragma unroll
      for (int i = 0; i < 4; ++i) af[i] = *reinterpret_cast<const bf16x8*>(As + rowA[i] + goff);
#pragma unroll
      for (int i = 0; i < 4; ++i) bfr[i] = *reinterpret_cast<const bf16x8*>(Bs + rowB[i] + goff);
#pragma unroll
      for (int i = 0; i < 4; ++i)
#pragma unroll
        for (int j = 0; j < 4; ++j)
          acc[i][j] = __builtin_amdgcn_mfma_f32_16x16x32_bf16(af[i], bfr[j], acc[i][j], 0, 0, 0);
    }
  }

#pragma unroll
  for (int j = 0; j < 4; ++j) {
    int oc = oc0 + wn * 64 + j * 16 + tx;
    if (oc >= 540) continue;
    float bv = bias[oc];
#pragma unroll
    for (int i = 0; i < 4; ++i) {
      f32x4 v = acc[i][j];
#pragma unroll
      for (int r = 0; r < 4; ++r) {
        int px = px0 + wm * 64 + i * 16 + quad * 4 + r;
        int n = px / 196, q = px - n * 196;
        int idx = (n * 540 + oc) * 196 + q;
        if constexpr (MODE == 0) {
          float val = tanhf(v[r] + bv);
          marr[idx] = val;
          int y = q / 14, x = q - y * 14;
          git[((n * 16 + 1 + y) * 16 + 1 + x) * CIPAD + 540 + oc] = f2bf(val);
        } else {
          float gv = v[r] + bv;
          float gamma = 1.f / (1.f + expf(-gv));
          out[idx] = tclip[idx] + gamma * marr[idx];
        }
      }
    }
  }
}

// ---------------- launcher ----------------
extern "C" void kernel_launch(void* const* d_in, const int* in_sizes, int n_in,
                              void* d_out, int out_size, void* d_ws, size_t ws_size,
                              hipStream_t stream)
{
  const float* frames = (const float*)d_in[0];
  const float* t_clip = (const float*)d_in[1];
  const float* w1 = (const float*)d_in[2];
  const float* b1 = (const float*)d_in[3];
  const float* w2 = (const float*)d_in[4];
  const float* b2 = (const float*)d_in[5];
  const float* wg = (const float*)d_in[6];
  const float* bg = (const float*)d_in[7];
  float* out = (float*)d_out;
  char* ws = (char*)d_ws;

  float* A1 = (float*)(ws + OFF_A1);
  float* A2 = (float*)(ws + OFF_A2);
  int* HIST = (int*)(ws + OFF_HIST);
  float* SUMS = (float*)(ws + OFF_SUMS);
  float* INVS = (float*)(ws + OFF_INVS);
  float* BSUM = (float*)(ws + OFF_BSUM);
  float* EPIX = (float*)(ws + OFF_EPIX);
  u16* HBF = (u16*)(ws + OFF_HBF);
  u16* GIT = (u16*)(ws + OFF_GIT);
  u16* WGB = (u16*)(ws + OFF_WGB);
  u16* W2B = (u16*)(ws + OFF_W2B);
  float* MARR = (float*)(ws + OFF_MARR);

  // zero hist+sums and the padded gi tensor (ws is poisoned each call)
  hipMemsetAsync(ws + OFF_HIST, 0, SZ_HIST + 768, stream);
  hipMemsetAsync(ws + OFF_GIT, 0, SZ_GIT, stream);

  // weight packs + t_clip -> gi (independent of SWT chain)
  pack_wg_kernel<<<640, 256, 0, stream>>>(wg, WGB);
  pack_w2_kernel<<<1440, 256, 0, stream>>>(w2, W2B);
  fill_git_kernel<<<dim3(4, 9, 64), 256, 0, stream>>>(t_clip, GIT);

  // SWT cascade with fused histograms + pooling (A3 never materialized)
  swt2_kernel<1><<<dim3(14, PLANES), 256, 0, stream>>>(frames, A1, HIST, SUMS, BSUM);
  swt2_kernel<2><<<dim3(14, PLANES), 256, 0, stream>>>(A1, A2, HIST, SUMS, BSUM);
  swt2_kernel<3><<<dim3(14, PLANES), 256, 0, stream>>>(A2, nullptr, HIST, SUMS, BSUM);
  quant_kernel<<<1920, 256, 0, stream>>>(HIST, INVS);
  epix_kernel<<<1568, 256, 0, stream>>>(BSUM, SUMS, INVS, EPIX);

  // MLP + gated conv
  gemm1_kernel<<<dim3(196, 5), 256, 0, stream>>>(EPIX, w1, b1, HBF);
  mfma_gemm_kernel<0><<<dim3(98, 5), 256, 0, stream>>>(HBF, W2B, b2, nullptr, MARR, GIT, nullptr);
  mfma_gemm_kernel<1><<<520, 256, 0, stream>>>(GIT, WGB, bg, t_clip, MARR, nullptr, out);
}